// Round 7
// baseline (169.082 us; speedup 1.0000x reference)
//
#include <hip/hip_runtime.h>
#include <stdint.h>

#define N_SITES 100000
#define NPAD    100032   // N rounded up to multiple of 64
#define CIN 64
#define CMID 384
#define COUT 64
#define SHIFT 16

typedef int   v4i __attribute__((ext_vector_type(4)));
typedef unsigned int v4u __attribute__((ext_vector_type(4)));
typedef float v4f __attribute__((ext_vector_type(4)));

// ---------------------------------------------------------------------------
// pack_w (192 blocks): w1p/w3p MFMA fragment order (byte(l,b) of tile t =
// W[(l>>4)*16+b][t*16+(l&15)]), wdw -> int32 [9][384], q-arrays to int,
// zero sentinel row. Weight-only: feats conversion now fused into k1.
// ---------------------------------------------------------------------------
__global__ __launch_bounds__(256) void pack_w(
    const float* __restrict__ w1, const float* __restrict__ w3,
    const float* __restrict__ b1, const float* __restrict__ s1,
    const float* __restrict__ b2, const float* __restrict__ s2,
    const float* __restrict__ b3, const float* __restrict__ s3,
    const float* __restrict__ wdw,
    int8_t* __restrict__ w1p, int8_t* __restrict__ w3p,
    int* __restrict__ q1, int* __restrict__ q3,
    int* __restrict__ wdw32, int* __restrict__ q2b, int* __restrict__ q2s,
    int8_t* __restrict__ x1s)
{
    int o = blockIdx.x * 256 + threadIdx.x;
    if (o < 24 * 64 * 16) {                       // w1p: [t=24][l=64][b=16]
        int t = o >> 10, l = (o >> 4) & 63, b = o & 15;
        int k = ((l >> 4) << 4) + b;
        int col = t * 16 + (l & 15);
        w1p[o] = (int8_t)__float2int_rn(w1[k * CMID + col]);
    }
    int o3 = o - 24 * 64 * 16;
    if (o3 >= 0 && o3 < 6 * 4 * 64 * 16) {        // w3p: [ks=6][t=4][l=64][b=16]
        int ks = o3 >> 12, t = (o3 >> 10) & 3;
        int l = (o3 >> 4) & 63, b = o3 & 15;
        int k = ks * 64 + ((l >> 4) << 4) + b;
        int col = t * 16 + (l & 15);
        w3p[o3] = (int8_t)__float2int_rn(w3[k * COUT + col]);
    }
    if (o < 9 * CMID)                              // wdw32: [k][c] int32
        wdw32[o] = __float2int_rn(wdw[o]);
    if (o < CMID) {
        q1[o] = __float2int_rn(b1[o]);
        q1[CMID + o] = __float2int_rn(s1[o]);
        q2b[o] = __float2int_rn(b2[o]);
        q2s[o] = __float2int_rn(s2[o]);
        x1s[(size_t)N_SITES * CMID + o] = 0;       // zero sentinel row
    }
    if (o < COUT) {
        q3[o] = __float2int_rn(b3[o]);
        q3[COUT + o] = __float2int_rn(s3[o]);
    }
}

// ---------------------------------------------------------------------------
// K1: fused f32->i8 convert + 1x1 expand MFMA. A = w1p (channel rows),
// B = feats row fragment built in-register (r4-proven construction).
// Lane owns 4 consecutive channels of ONE site -> 24 packed dword stores
// (r6-proven layout, absmax 0).
// ---------------------------------------------------------------------------
__global__ __launch_bounds__(256) void k1_mfma(
    const float* __restrict__ feats, const int8_t* __restrict__ w1p,
    const int* __restrict__ q1, int8_t* __restrict__ x1s)
{
    const int lane = threadIdx.x & 63;
    const int wave = threadIdx.x >> 6;
    const int site = blockIdx.x * 64 + wave * 16 + (lane & 15);
    const int rsite = min(site, N_SITES - 1);      // clamp loads (feats is N*64)
    const bool ok = site < N_SITES;
    const int cb = (lane >> 4) << 2;               // channel sub-offset 0,4,8,12

    // B-fragment: 16 floats of this site's row, k-window (lane>>4)*16 -> 16 bytes
    v4i b;
    const float* fp = feats + (size_t)rsite * CIN + ((lane >> 4) << 4);
#pragma unroll
    for (int j = 0; j < 4; ++j) {
        const v4f f = *(const v4f*)(fp + 4 * j);
        uint32_t pk = (uint32_t)(__float2int_rn(f[0]) & 255)
                    | ((uint32_t)(__float2int_rn(f[1]) & 255) << 8)
                    | ((uint32_t)(__float2int_rn(f[2]) & 255) << 16)
                    | ((uint32_t)__float2int_rn(f[3]) << 24);
        b[j] = (int)pk;
    }

    const v4i* ap = (const v4i*)w1p + lane;
    int8_t* orow = x1s + (size_t)rsite * CMID;
#pragma unroll
    for (int t = 0; t < 24; ++t) {
        v4i a = ap[t * 64];
        v4i acc = {0, 0, 0, 0};
        acc = __builtin_amdgcn_mfma_i32_16x16x64_i8(a, b, acc, 0, 0, 0);
        const int co = t * 16 + cb;                // 4 consecutive channels
        const v4i bi = *(const v4i*)(q1 + co);
        const v4i si = *(const v4i*)(q1 + CMID + co);
        uint32_t wrd = 0;
#pragma unroll
        for (int r = 0; r < 4; ++r) {
            int v = ((acc[r] + bi[r]) * si[r] + (1 << (SHIFT - 1))) >> SHIFT;
            v = max(0, min(127, v));
            wrd |= (uint32_t)v << (8 * r);
        }
        if (ok) *(uint32_t*)(orow + co) = wrd;
    }
}

// ---------------------------------------------------------------------------
// K2: 3x3 depthwise. Thread mapping, gather order, tap-major consumption
// IDENTICAL to the proven 43us shape. Only changes: weights pre-unpacked to
// int32 (kills the weight bfe: 3 -> 2 VALU/MAC), separate int b/s arrays
// (kills sext unpack), __mul24-fused rounding, med3 clamp.
// ---------------------------------------------------------------------------
__global__ __launch_bounds__(256) void k2_dw(
    const int8_t* __restrict__ x1s, const int* __restrict__ nbr,
    const int* __restrict__ wdw32, const int* __restrict__ q2b,
    const int* __restrict__ q2s, int8_t* __restrict__ x2s)
{
    const int g = blockIdx.x * 256 + threadIdx.x;
    const int site = g / 24;
    const int c0 = (g - site * 24) << 4;           // channel base, 0..368

    const int* nb = &nbr[site * 9];
    int idx[9];
#pragma unroll
    for (int k = 0; k < 9; ++k) idx[k] = nb[k];

    v4u V[9];
#pragma unroll
    for (int k = 0; k < 9; ++k) {
        const int off = (idx[k] << 8) + (idx[k] << 7) + c0;   // idx*384 + c0
        V[k] = *(const v4u*)(x1s + off);
    }

    int acc[16];
#pragma unroll
    for (int j = 0; j < 16; ++j) acc[j] = 0;

#pragma unroll
    for (int k = 0; k < 9; ++k) {
        v4i W[4];
#pragma unroll
        for (int j = 0; j < 4; ++j)
            W[j] = *(const v4i*)(wdw32 + k * CMID + c0 + 4 * j);
#pragma unroll
        for (int j = 0; j < 4; ++j) {
#pragma unroll
            for (int b = 0; b < 4; ++b) {
                const int v = (int)(uint8_t)(V[k][j] >> (8 * b));  // [0,127]
                acc[j * 4 + b] = __mul24(v, W[j][b]) + acc[j * 4 + b];
            }
        }
    }

    v4u outw;
#pragma unroll
    for (int j = 0; j < 4; ++j) {
        const v4i bb = *(const v4i*)(q2b + c0 + 4 * j);
        const v4i ss = *(const v4i*)(q2s + c0 + 4 * j);
        uint32_t wrd = 0;
#pragma unroll
        for (int b = 0; b < 4; ++b) {
            // acc+bb < 2^18, ss <= 64 -> 24-bit mul exact
            int t = (__mul24(acc[j * 4 + b] + bb[b], ss[b])
                     + (1 << (SHIFT - 1))) >> SHIFT;
            t = max(0, min(127, t));               // -> v_med3
            wrd |= (uint32_t)t << (8 * b);
        }
        outw[j] = wrd;
    }
    *(v4u*)(x2s + (site << 8) + (site << 7) + c0) = outw;
}

// ---------------------------------------------------------------------------
// K3: 1x1 project, swapped operands (r6-proven): A = w3p, B = x2 row
// fragment; lane owns 4 consecutive couts of one site -> 4 float4 stores.
// ---------------------------------------------------------------------------
__global__ __launch_bounds__(256) void k3_mfma(
    const int8_t* __restrict__ x2s, const int8_t* __restrict__ w3p,
    const int* __restrict__ q3, float* __restrict__ out)
{
    const int lane = threadIdx.x & 63;
    const int wave = threadIdx.x >> 6;
    const int site = blockIdx.x * 64 + wave * 16 + (lane & 15);
    const int cb = (lane >> 4) << 2;               // cout sub-offset 0,4,8,12
    const int8_t* xrow = x2s + (size_t)site * CMID + ((lane >> 4) << 4);

    v4i acc[4] = {{0,0,0,0},{0,0,0,0},{0,0,0,0},{0,0,0,0}};
#pragma unroll
    for (int ks = 0; ks < 6; ++ks) {
        const v4i bfr = *(const v4i*)(xrow + ks * 64);
#pragma unroll
        for (int t = 0; t < 4; ++t) {
            const v4i afr = *((const v4i*)w3p + (ks * 4 + t) * 64 + lane);
            acc[t] = __builtin_amdgcn_mfma_i32_16x16x64_i8(afr, bfr, acc[t], 0, 0, 0);
        }
    }
    if (site < N_SITES) {
        float* orow = out + (size_t)site * COUT;
#pragma unroll
        for (int t = 0; t < 4; ++t) {
            const int co = t * 16 + cb;            // 4 consecutive couts
            const v4i bo = *(const v4i*)(q3 + co);
            const v4i so = *(const v4i*)(q3 + COUT + co);
            v4f o;
#pragma unroll
            for (int r = 0; r < 4; ++r) {
                int v = ((acc[t][r] + bo[r]) * so[r] + (1 << (SHIFT - 1))) >> SHIFT;
                v = max(-128, min(127, v));
                o[r] = (float)v;
            }
            *(v4f*)(orow + co) = o;
        }
    }
}

extern "C" void kernel_launch(void* const* d_in, const int* in_sizes, int n_in,
                              void* d_out, int out_size, void* d_ws, size_t ws_size,
                              hipStream_t stream) {
    const float* feats = (const float*)d_in[0];
    const float* w1    = (const float*)d_in[1];
    const float* b1    = (const float*)d_in[2];
    const float* s1    = (const float*)d_in[3];
    const float* wdw   = (const float*)d_in[4];
    const float* b2    = (const float*)d_in[5];
    const float* s2    = (const float*)d_in[6];
    const float* w3    = (const float*)d_in[7];
    const float* b3    = (const float*)d_in[8];
    const float* s3    = (const float*)d_in[9];
    const int*   nbr   = (const int*)d_in[10];
    float* out = (float*)d_out;

    int8_t* x1s   = (int8_t*)d_ws;                     // NPAD*384 (sentinel row inside)
    int8_t* x2s   = x1s + (size_t)NPAD * CMID;         // NPAD*384
    int8_t* w1p   = x2s + (size_t)NPAD * CMID;         // 24576
    int8_t* w3p   = w1p + 24 * 64 * 16;                // 24576
    int*    q1    = (int*)(w3p + 6 * 4 * 64 * 16);     // 2*384 ints
    int*    q3    = q1 + 2 * CMID;                     // 2*64 ints
    int*    wdw32 = q3 + 2 * COUT;                     // 9*384 ints
    int*    q2b   = wdw32 + 9 * CMID;                  // 384 ints
    int*    q2s   = q2b + CMID;                        // 384 ints

    pack_w<<<192, 256, 0, stream>>>(w1, w3, b1, s1, b2, s2, b3, s3, wdw,
                                    w1p, w3p, q1, q3, wdw32, q2b, q2s, x1s);
    k1_mfma<<<NPAD / 64, 256, 0, stream>>>(feats, w1p, q1, x1s);
    k2_dw<<<N_SITES * 24 / 256, 256, 0, stream>>>(x1s, nbr, wdw32, q2b, q2s, x2s);
    k3_mfma<<<NPAD / 64, 256, 0, stream>>>(x2s, w3p, q3, out);
}

// Round 8
// 82.648 us; speedup vs baseline: 2.0458x; 2.0458x over previous
//
#include <hip/hip_runtime.h>
#include <stdint.h>

#define N_SITES 100000
#define NPAD    100032   // N rounded up to multiple of 64
#define CIN 64
#define CMID 384
#define COUT 64
#define SHIFT 16

typedef int   v4i __attribute__((ext_vector_type(4)));
typedef unsigned int v4u __attribute__((ext_vector_type(4)));
typedef float v4f __attribute__((ext_vector_type(4)));

// ---------------------------------------------------------------------------
// pack_w (192 blocks): w1p/w3p MFMA fragment order (byte(l,b) of tile t =
// W[(l>>4)*16+b][t*16+(l&15)]), wdw8 int8 [9][384] (r6-proven for k2),
// bs2 packed (b lo16 | s hi16), q1/q3 ints, zero sentinel row.
// ---------------------------------------------------------------------------
__global__ __launch_bounds__(256) void pack_w(
    const float* __restrict__ w1, const float* __restrict__ w3,
    const float* __restrict__ b1, const float* __restrict__ s1,
    const float* __restrict__ b2, const float* __restrict__ s2,
    const float* __restrict__ b3, const float* __restrict__ s3,
    const float* __restrict__ wdw,
    int8_t* __restrict__ w1p, int8_t* __restrict__ w3p,
    int* __restrict__ q1, int* __restrict__ q3,
    int8_t* __restrict__ wdw8, int* __restrict__ bs2,
    int8_t* __restrict__ x1s)
{
    int o = blockIdx.x * 256 + threadIdx.x;
    if (o < 24 * 64 * 16) {                       // w1p: [t=24][l=64][b=16]
        int t = o >> 10, l = (o >> 4) & 63, b = o & 15;
        int k = ((l >> 4) << 4) + b;
        int col = t * 16 + (l & 15);
        w1p[o] = (int8_t)__float2int_rn(w1[k * CMID + col]);
    }
    int o3 = o - 24 * 64 * 16;
    if (o3 >= 0 && o3 < 6 * 4 * 64 * 16) {        // w3p: [ks=6][t=4][l=64][b=16]
        int ks = o3 >> 12, t = (o3 >> 10) & 3;
        int l = (o3 >> 4) & 63, b = o3 & 15;
        int k = ks * 64 + ((l >> 4) << 4) + b;
        int col = t * 16 + (l & 15);
        w3p[o3] = (int8_t)__float2int_rn(w3[k * COUT + col]);
    }
    if (o < 9 * CMID)                              // wdw8: [k][c] int8
        wdw8[o] = (int8_t)__float2int_rn(wdw[o]);
    if (o < CMID) {
        q1[o] = __float2int_rn(b1[o]);
        q1[CMID + o] = __float2int_rn(s1[o]);
        int bb = __float2int_rn(b2[o]);            // [-1024,1024] fits i16
        int ss = __float2int_rn(s2[o]);            // [1,64]
        bs2[o] = (bb & 0xFFFF) | (ss << 16);
        x1s[(size_t)N_SITES * CMID + o] = 0;       // zero sentinel row
    }
    if (o < COUT) {
        q3[o] = __float2int_rn(b3[o]);
        q3[COUT + o] = __float2int_rn(s3[o]);
    }
}

// ---------------------------------------------------------------------------
// K1: fused f32->i8 convert + 1x1 expand MFMA. Results land in a padded LDS
// tile (pitch 400 B: write banks 2-way = free), then one contiguous,
// fully-coalesced 24 KB block store (replaces 24 scattered 16 B stores/site).
// ---------------------------------------------------------------------------
__global__ __launch_bounds__(256) void k1_mfma(
    const float* __restrict__ feats, const int8_t* __restrict__ w1p,
    const int* __restrict__ q1, int8_t* __restrict__ x1s)
{
    __shared__ int8_t xt[64 * 400];                // 25.6 KB
    const int lane = threadIdx.x & 63;
    const int wave = threadIdx.x >> 6;
    const int sl = wave * 16 + (lane & 15);        // local site 0..63
    const int site = blockIdx.x * 64 + sl;
    const int rsite = min(site, N_SITES - 1);      // clamp loads
    const int cb = (lane >> 4) << 2;               // channel sub-offset 0,4,8,12

    // B-fragment: 16 floats of this site's row, k-window (lane>>4)*16 -> 16 bytes
    v4i b;
    const float* fp = feats + (size_t)rsite * CIN + ((lane >> 4) << 4);
#pragma unroll
    for (int j = 0; j < 4; ++j) {
        const v4f f = *(const v4f*)(fp + 4 * j);
        uint32_t pk = (uint32_t)(__float2int_rn(f[0]) & 255)
                    | ((uint32_t)(__float2int_rn(f[1]) & 255) << 8)
                    | ((uint32_t)(__float2int_rn(f[2]) & 255) << 16)
                    | ((uint32_t)__float2int_rn(f[3]) << 24);
        b[j] = (int)pk;
    }

    const v4i* ap = (const v4i*)w1p + lane;
#pragma unroll
    for (int t = 0; t < 24; ++t) {
        v4i a = ap[t * 64];
        v4i acc = {0, 0, 0, 0};
        acc = __builtin_amdgcn_mfma_i32_16x16x64_i8(a, b, acc, 0, 0, 0);
        const int co = t * 16 + cb;                // 4 consecutive channels
        const v4i bi = *(const v4i*)(q1 + co);
        const v4i si = *(const v4i*)(q1 + CMID + co);
        uint32_t wrd = 0;
#pragma unroll
        for (int r = 0; r < 4; ++r) {
            int v = ((acc[r] + bi[r]) * si[r] + (1 << (SHIFT - 1))) >> SHIFT;
            v = max(0, min(127, v));
            wrd |= (uint32_t)v << (8 * r);
        }
        *(uint32_t*)(xt + sl * 400 + co) = wrd;
    }
    __syncthreads();

    // contiguous coalesced copy-out: 64 rows x 384 B = 24 KB
    int8_t* dst = x1s + (size_t)blockIdx.x * 64 * CMID;
#pragma unroll
    for (int it = 0; it < 6; ++it) {
        const int lin = it * 4096 + threadIdx.x * 16;   // byte index, < 24576
        const int r = lin / 384;
        const int c = lin - r * 384;
        const v4u val = *(const v4u*)(xt + r * 400 + c);
        if (blockIdx.x * 64 + r < N_SITES)              // protect sentinel/pad
            *(v4u*)(dst + lin) = val;
    }
}

// ---------------------------------------------------------------------------
// K2: 3x3 depthwise — EXACT r6 text (proven 43 us twice). thread = 16
// channels of one site; tap-major MAC loop overlaps in-flight gathers;
// packed int8 weights (16 B/tap).
// ---------------------------------------------------------------------------
__global__ __launch_bounds__(256) void k2_dw(
    const int8_t* __restrict__ x1s, const int* __restrict__ nbr,
    const int8_t* __restrict__ wdw8, const int* __restrict__ bs2,
    int8_t* __restrict__ x2s)
{
    const int g = blockIdx.x * 256 + threadIdx.x;
    const int site = g / 24;
    const int c0 = (g - site * 24) << 4;           // channel base, 0..368

    const int* nb = &nbr[site * 9];
    int idx[9];
#pragma unroll
    for (int k = 0; k < 9; ++k) idx[k] = nb[k];

    v4u V[9];
#pragma unroll
    for (int k = 0; k < 9; ++k) {
        const int off = (idx[k] << 8) + (idx[k] << 7) + c0;   // idx*384 + c0
        V[k] = *(const v4u*)(x1s + off);
    }

    int acc[16];
#pragma unroll
    for (int j = 0; j < 16; ++j) acc[j] = 0;

#pragma unroll
    for (int k = 0; k < 9; ++k) {
        const v4u W = *(const v4u*)(wdw8 + k * CMID + c0);
#pragma unroll
        for (int j = 0; j < 4; ++j) {
#pragma unroll
            for (int b = 0; b < 4; ++b) {
                const int v = (int)(uint8_t)(V[k][j] >> (8 * b));  // [0,127]
                const int w = (int)(int8_t)(W[j] >> (8 * b));      // [-128,127]
                acc[j * 4 + b] += v * w;           // v_mad_i32_i24
            }
        }
    }

    const v4i BS0 = *(const v4i*)(bs2 + c0);
    const v4i BS1 = *(const v4i*)(bs2 + c0 + 4);
    const v4i BS2 = *(const v4i*)(bs2 + c0 + 8);
    const v4i BS3 = *(const v4i*)(bs2 + c0 + 12);
    const v4i BS[4] = {BS0, BS1, BS2, BS3};

    v4u outw;
#pragma unroll
    for (int j = 0; j < 4; ++j) {
        uint32_t wrd = 0;
#pragma unroll
        for (int b = 0; b < 4; ++b) {
            const int bsv = BS[j][b];
            const int bb = (bsv << 16) >> 16;      // sext low 16
            const int ss = bsv >> 16;              // sext high 16
            int t = ((acc[j * 4 + b] + bb) * ss + (1 << (SHIFT - 1))) >> SHIFT;
            t = max(0, min(127, t));
            wrd |= (uint32_t)t << (8 * b);
        }
        outw[j] = wrd;
    }
    *(v4u*)(x2s + (site << 8) + (site << 7) + c0) = outw;
}

// ---------------------------------------------------------------------------
// K3: 1x1 project MFMA; results via padded LDS tile (pitch 272 B) then one
// contiguous coalesced 16 KB block store (replaces 4 scattered float4/site).
// ---------------------------------------------------------------------------
__global__ __launch_bounds__(256) void k3_mfma(
    const int8_t* __restrict__ x2s, const int8_t* __restrict__ w3p,
    const int* __restrict__ q3, float* __restrict__ out)
{
    __shared__ float ot[64 * 68];                  // 17.4 KB
    const int lane = threadIdx.x & 63;
    const int wave = threadIdx.x >> 6;
    const int sl = wave * 16 + (lane & 15);
    const int site = blockIdx.x * 64 + sl;
    const int rsite = min(site, N_SITES - 1);
    const int cb = (lane >> 4) << 2;               // cout sub-offset 0,4,8,12
    const int8_t* xrow = x2s + (size_t)rsite * CMID + ((lane >> 4) << 4);

    v4i acc[4] = {{0,0,0,0},{0,0,0,0},{0,0,0,0},{0,0,0,0}};
#pragma unroll
    for (int ks = 0; ks < 6; ++ks) {
        const v4i bfr = *(const v4i*)(xrow + ks * 64);
#pragma unroll
        for (int t = 0; t < 4; ++t) {
            const v4i afr = *((const v4i*)w3p + (ks * 4 + t) * 64 + lane);
            acc[t] = __builtin_amdgcn_mfma_i32_16x16x64_i8(afr, bfr, acc[t], 0, 0, 0);
        }
    }
#pragma unroll
    for (int t = 0; t < 4; ++t) {
        const int co = t * 16 + cb;                // 4 consecutive couts
        const v4i bo = *(const v4i*)(q3 + co);
        const v4i so = *(const v4i*)(q3 + COUT + co);
        v4f o;
#pragma unroll
        for (int r = 0; r < 4; ++r) {
            int v = ((acc[t][r] + bo[r]) * so[r] + (1 << (SHIFT - 1))) >> SHIFT;
            v = max(-128, min(127, v));
            o[r] = (float)v;
        }
        *(v4f*)(&ot[sl * 68 + co]) = o;
    }
    __syncthreads();

    float* dst = out + (size_t)blockIdx.x * 64 * COUT;
#pragma unroll
    for (int it = 0; it < 4; ++it) {
        const int lin = it * 1024 + threadIdx.x * 4;    // float index, < 4096
        const int r = lin >> 6;
        const int c = lin & 63;
        const v4f val = *(const v4f*)(&ot[r * 68 + c]);
        if (blockIdx.x * 64 + r < N_SITES)
            *(v4f*)(dst + lin) = val;
    }
}

extern "C" void kernel_launch(void* const* d_in, const int* in_sizes, int n_in,
                              void* d_out, int out_size, void* d_ws, size_t ws_size,
                              hipStream_t stream) {
    const float* feats = (const float*)d_in[0];
    const float* w1    = (const float*)d_in[1];
    const float* b1    = (const float*)d_in[2];
    const float* s1    = (const float*)d_in[3];
    const float* wdw   = (const float*)d_in[4];
    const float* b2    = (const float*)d_in[5];
    const float* s2    = (const float*)d_in[6];
    const float* w3    = (const float*)d_in[7];
    const float* b3    = (const float*)d_in[8];
    const float* s3    = (const float*)d_in[9];
    const int*   nbr   = (const int*)d_in[10];
    float* out = (float*)d_out;

    int8_t* x1s   = (int8_t*)d_ws;                     // NPAD*384 (sentinel row inside)
    int8_t* x2s   = x1s + (size_t)NPAD * CMID;         // NPAD*384
    int8_t* w1p   = x2s + (size_t)NPAD * CMID;         // 24576
    int8_t* w3p   = w1p + 24 * 64 * 16;                // 24576
    int*    q1    = (int*)(w3p + 6 * 4 * 64 * 16);     // 2*384 ints
    int*    q3    = q1 + 2 * CMID;                     // 2*64 ints
    int8_t* wdw8  = (int8_t*)(q3 + 2 * COUT);          // 9*384 bytes
    int*    bs2   = (int*)(wdw8 + 9 * CMID);           // 384 ints

    pack_w<<<192, 256, 0, stream>>>(w1, w3, b1, s1, b2, s2, b3, s3, wdw,
                                    w1p, w3p, q1, q3, wdw8, bs2, x1s);
    k1_mfma<<<NPAD / 64, 256, 0, stream>>>(feats, w1p, q1, x1s);
    k2_dw<<<N_SITES * 24 / 256, 256, 0, stream>>>(x1s, nbr, wdw8, bs2, x2s);
    k3_mfma<<<NPAD / 64, 256, 0, stream>>>(x2s, w3p, q3, out);
}